// Round 11
// baseline (34.520 us; speedup 1.0000x reference)
//
#include <hip/hip_runtime.h>
#include <hip/hip_bf16.h>

// Problem constants (B,N,H,O) = (2,512,128,32)
#define NN 512
#define HH 128
#define OO 32

// 2*log2(e): tanh(x) = 1 - 2/(2^(KL*xa)*2^(KL*xb)+1) with x = xa+xb
#define KL 2.8853900817779268f

__device__ __forceinline__ float vexp2(float x) {
    float r; asm("v_exp_f32 %0, %1" : "=v"(r) : "v"(x)); return r;
}
__device__ __forceinline__ float vrcp(float x) {
    float r; asm("v_rcp_f32 %0, %1" : "=v"(r) : "v"(x)); return r;
}
__device__ __forceinline__ float tanh_fast(float x) {
    float e = vexp2(KL * x);
    return 1.0f - 2.0f * vrcp(e + 1.0f);
}
__device__ __forceinline__ float red8(float v) {   // sum within 8-lane group
    v += __shfl_xor(v, 1, 64); v += __shfl_xor(v, 2, 64); v += __shfl_xor(v, 4, 64);
    return v;
}
// Rotated 16-dot: weights pre-rotated at load; LDS x read at rotated offsets
// so each kq group hits a distinct bank quad (conflict-free).
__device__ __forceinline__ float dot16r(const float4* w, const float* x, int rot) {
    float a = 0;
#pragma unroll
    for (int ii = 0; ii < 4; ii++) {
        int i = (ii + rot) & 3;
        float4 xv = *(const float4*)(x + i * 4);
        a = fmaf(xv.x, w[ii].x, a); a = fmaf(xv.y, w[ii].y, a);
        a = fmaf(xv.z, w[ii].z, a); a = fmaf(xv.w, w[ii].w, a);
    }
    return a;
}
__device__ __forceinline__ unsigned short f2bf(float x) {   // RNE f32->bf16
    unsigned u = __float_as_uint(x);
    u += 0x7fffu + ((u >> 16) & 1u);
    return (unsigned short)(u >> 16);
}
__device__ __forceinline__ float bf_lo(unsigned u) { return __uint_as_float((u & 0xffffu) << 16); }
__device__ __forceinline__ float bf_hi(unsigned u) { return __uint_as_float(u & 0xffff0000u); }

// ---------------------------------------------------------------------------
// K1: ALL producer work. 256 blocks x 1024 thr, 4 rows/block. (= R10)
//   qP/cP packed [bid][h][4] ; Ezj[gr][h] bf16 ; kTp[b][h][jp] u32 = bf16 pair.
// ---------------------------------------------------------------------------
__global__ __launch_bounds__(1024, 4) void prep_kernel(
    const float* __restrict__ z, const float* __restrict__ s_t,
    const float* __restrict__ W1, const float* __restrict__ b1,
    const float* __restrict__ Wq, const float* __restrict__ bq,
    const float* __restrict__ Wk, const float* __restrict__ bk,
    float* __restrict__ qP, float* __restrict__ cP,
    unsigned short* __restrict__ EzjG, unsigned* __restrict__ kTp) {
    __shared__ float zrow[4][HH];
    __shared__ float srow[4][OO];
    int t = threadIdx.x, bid = blockIdx.x;
    int r0 = bid * 4, b = bid >> 7, i0 = (bid & 127) * 4;
    int kq = t & 7, h = t >> 3, rot = (kq >> 1) & 3;

    const float4* WqP = (const float4*)(Wq + (size_t)h * HH) + kq * 4;
    const float4* WiP = (const float4*)(W1 + (size_t)h * 2 * HH) + kq * 4;
    const float4* WjP = (const float4*)(W1 + (size_t)h * 2 * HH + HH) + kq * 4;
    float4 wq[4], wi[4], wj[4];
#pragma unroll
    for (int ii = 0; ii < 4; ii++) {
        wq[ii] = WqP[(ii + rot) & 3];
        wi[ii] = WiP[(ii + rot) & 3];
        wj[ii] = WjP[(ii + rot) & 3];
    }
    float4 wk = ((const float4*)(Wk + (size_t)h * OO))[kq];
    float vbq = bq[h], vb1 = b1[h], vbk = bk[h];

    if (t < 4 * HH) zrow[t >> 7][t & 127] = z[(size_t)r0 * HH + t];
    else if (t < 4 * HH + 4 * OO) {
        int u = t - 4 * HH;
        srow[u >> 5][u & 31] = s_t[(size_t)r0 * OO + u];
    }
    __syncthreads();

    {   // q -> qP
        float a0 = red8(dot16r(wq, &zrow[0][kq * 16], rot));
        float a1 = red8(dot16r(wq, &zrow[1][kq * 16], rot));
        float a2 = red8(dot16r(wq, &zrow[2][kq * 16], rot));
        float a3 = red8(dot16r(wq, &zrow[3][kq * 16], rot));
        if (kq == 0) {
            float* qp = qP + (size_t)bid * 512 + h * 4;
            qp[0] = a0 + vbq; qp[1] = a1 + vbq; qp[2] = a2 + vbq; qp[3] = a3 + vbq;
        }
    }
    {   // Ezi -> cP
        float a0 = red8(dot16r(wi, &zrow[0][kq * 16], rot));
        float a1 = red8(dot16r(wi, &zrow[1][kq * 16], rot));
        float a2 = red8(dot16r(wi, &zrow[2][kq * 16], rot));
        float a3 = red8(dot16r(wi, &zrow[3][kq * 16], rot));
        if (kq == 0) {
            float* cp = cP + (size_t)bid * 512 + h * 4;
            cp[0] = vexp2(KL * (a0 + vb1)); cp[1] = vexp2(KL * (a1 + vb1));
            cp[2] = vexp2(KL * (a2 + vb1)); cp[3] = vexp2(KL * (a3 + vb1));
        }
    }
    {   // Ezj -> bf16
        float a0 = red8(dot16r(wj, &zrow[0][kq * 16], rot));
        float a1 = red8(dot16r(wj, &zrow[1][kq * 16], rot));
        float a2 = red8(dot16r(wj, &zrow[2][kq * 16], rot));
        float a3 = red8(dot16r(wj, &zrow[3][kq * 16], rot));
        if (kq == 0) {
            EzjG[(size_t)(r0 + 0) * HH + h] = f2bf(vexp2(KL * a0));
            EzjG[(size_t)(r0 + 1) * HH + h] = f2bf(vexp2(KL * a1));
            EzjG[(size_t)(r0 + 2) * HH + h] = f2bf(vexp2(KL * a2));
            EzjG[(size_t)(r0 + 3) * HH + h] = f2bf(vexp2(KL * a3));
        }
    }
    {   // k -> kTp (bf16 pair-packed, transposed)
        float4 s0 = *(const float4*)&srow[0][kq * 4];
        float4 s1 = *(const float4*)&srow[1][kq * 4];
        float4 s2 = *(const float4*)&srow[2][kq * 4];
        float4 s3 = *(const float4*)&srow[3][kq * 4];
        float a0 = red8(s0.x * wk.x + s0.y * wk.y + s0.z * wk.z + s0.w * wk.w);
        float a1 = red8(s1.x * wk.x + s1.y * wk.y + s1.z * wk.z + s1.w * wk.w);
        float a2 = red8(s2.x * wk.x + s2.y * wk.y + s2.z * wk.z + s2.w * wk.w);
        float a3 = red8(s3.x * wk.x + s3.y * wk.y + s3.z * wk.z + s3.w * wk.w);
        if (kq == 0) {
            unsigned p01 = (unsigned)f2bf(a0 + vbk) | ((unsigned)f2bf(a1 + vbk) << 16);
            unsigned p23 = (unsigned)f2bf(a2 + vbk) | ((unsigned)f2bf(a3 + vbk) << 16);
            unsigned* kp = kTp + ((size_t)b * HH + h) * 256 + (i0 >> 1);
            kp[0] = p01; kp[1] = p23;
        }
    }
}

// ---------------------------------------------------------------------------
// K2: consumer, barrier-free core. 256 blocks x 1024 thr, 4 rows/block.
// Each of the 16 waves owns a 32-j slice end-to-end:
//   scores (lane=(jp,hq), 2 shfl_xor h-reduce) -> exp (registers, no max)
//   -> slice-sum (4 shfl_xor) -> e to wave-private eBuf (no barrier)
//   -> D rcp-core for own slice (e via broadcast reads, no barrier).
// Only 5 block barriers: post-stage, post-core, post-UL, and 2 in E.
// Normalization folded into UL: U = 1 - 2*sum/S.
// ---------------------------------------------------------------------------
__global__ __launch_bounds__(1024, 4) void fused_kernel(
    const float* __restrict__ qP, const float* __restrict__ cP,
    const unsigned* __restrict__ kTp, const unsigned short* __restrict__ EzjG,
    const float* __restrict__ W2, const float* __restrict__ b2,
    const float* __restrict__ W3, const float* __restrict__ b3,
    const float* __restrict__ W4, const float* __restrict__ b4,
    float* __restrict__ out) {
    __shared__ float q4T[HH][4];         // 2KB
    __shared__ float c4T[HH][4];         // 2KB
    __shared__ float eBuf[16][4][32];    // 8KB  per-wave unnormalized e
    __shared__ float sliceS[16][4];      // 256B per-wave row sums
    __shared__ float part[16][4][HH];    // 32KB D partials
    __shared__ float UL[4][HH];          // 2KB
    __shared__ float aggL[4][HH];        // 2KB
    __shared__ float h1L[4][HH];         // 2KB

    int t = threadIdx.x, bid = blockIdx.x;
    int b = bid >> 7, i0 = (bid & 127) * 4, r0 = bid * 4;
    int w = t >> 6, lane = t & 63;

    // ---- A: stage q/Ezi packed (coalesced) ----
    if (t < 512) ((float*)q4T)[t] = qP[(size_t)bid * 512 + t];
    else         ((float*)c4T)[t - 512] = cP[(size_t)bid * 512 + (t - 512)];
    __syncthreads();

    // ================= per-wave barrier-free core =================
    {
        // ---- scores for own slice: lane = (jp_local, hq) ----
        int jp_local = lane & 15, hq = lane >> 4;
        int jp = w * 16 + jp_local, h0 = hq * 32;
        const unsigned* kb = kTp + ((size_t)b * HH + h0) * 256 + jp;
        float s0l = 0, s1l = 0, s2l = 0, s3l = 0;
        float s0h = 0, s1h = 0, s2h = 0, s3h = 0;
#pragma unroll 8
        for (int hh = 0; hh < 32; hh++) {
            unsigned u = kb[(size_t)hh * 256];
            float kl = bf_lo(u), kh = bf_hi(u);
            float4 qv = *(const float4*)q4T[h0 + hh];   // broadcast
            s0l = fmaf(qv.x, kl, s0l); s1l = fmaf(qv.y, kl, s1l);
            s2l = fmaf(qv.z, kl, s2l); s3l = fmaf(qv.w, kl, s3l);
            s0h = fmaf(qv.x, kh, s0h); s1h = fmaf(qv.y, kh, s1h);
            s2h = fmaf(qv.z, kh, s2h); s3h = fmaf(qv.w, kh, s3h);
        }
        // reduce across the 4 hq groups (bits 4,5 of lane)
        s0l += __shfl_xor(s0l, 16, 64); s0l += __shfl_xor(s0l, 32, 64);
        s1l += __shfl_xor(s1l, 16, 64); s1l += __shfl_xor(s1l, 32, 64);
        s2l += __shfl_xor(s2l, 16, 64); s2l += __shfl_xor(s2l, 32, 64);
        s3l += __shfl_xor(s3l, 16, 64); s3l += __shfl_xor(s3l, 32, 64);
        s0h += __shfl_xor(s0h, 16, 64); s0h += __shfl_xor(s0h, 32, 64);
        s1h += __shfl_xor(s1h, 16, 64); s1h += __shfl_xor(s1h, 32, 64);
        s2h += __shfl_xor(s2h, 16, 64); s2h += __shfl_xor(s2h, 32, 64);
        s3h += __shfl_xor(s3h, 16, 64); s3h += __shfl_xor(s3h, 32, 64);

        // ---- exp (no max pass: |score| small) + diagonal mask ----
        const float sc = 0.08838834764831845f;  // 1/sqrt(128)
        float e0l = __expf(s0l * sc), e1l = __expf(s1l * sc);
        float e2l = __expf(s2l * sc), e3l = __expf(s3l * sc);
        float e0h = __expf(s0h * sc), e1h = __expf(s1h * sc);
        float e2h = __expf(s2h * sc), e3h = __expf(s3h * sc);
        int jl = jp * 2, jh = jl + 1;
        if (jl == i0 + 0) e0l = 0.0f;  if (jh == i0 + 0) e0h = 0.0f;
        if (jl == i0 + 1) e1l = 0.0f;  if (jh == i0 + 1) e1h = 0.0f;
        if (jl == i0 + 2) e2l = 0.0f;  if (jh == i0 + 2) e2h = 0.0f;
        if (jl == i0 + 3) e3l = 0.0f;  if (jh == i0 + 3) e3h = 0.0f;

        // ---- slice sums (reduce over jp_local bits 0..3; replicated ok) ----
        float ts0 = e0l + e0h, ts1 = e1l + e1h, ts2 = e2l + e2h, ts3 = e3l + e3h;
#pragma unroll
        for (int m = 1; m <= 8; m <<= 1) {
            ts0 += __shfl_xor(ts0, m, 64); ts1 += __shfl_xor(ts1, m, 64);
            ts2 += __shfl_xor(ts2, m, 64); ts3 += __shfl_xor(ts3, m, 64);
        }
        if (lane == 0) {
            sliceS[w][0] = ts0; sliceS[w][1] = ts1;
            sliceS[w][2] = ts2; sliceS[w][3] = ts3;
        }
        // ---- write e to wave-private eBuf (no block barrier needed) ----
        if (hq == 0) {
            *(float2*)&eBuf[w][0][2 * jp_local] = make_float2(e0l, e0h);
            *(float2*)&eBuf[w][1][2 * jp_local] = make_float2(e1l, e1h);
            *(float2*)&eBuf[w][2][2 * jp_local] = make_float2(e2l, e2h);
            *(float2*)&eBuf[w][3][2 * jp_local] = make_float2(e3l, e3h);
        }

        // ---- D: rcp core for own slice; e via same-wave LDS broadcast ----
        int hp = lane * 2, jb = w * 32;
        const unsigned* zbU = (const unsigned*)EzjG + (size_t)b * NN * 64 + lane;
        float4 cA = *(const float4*)c4T[hp];
        float4 cB = *(const float4*)c4T[hp + 1];
        float a0A = 0, a1A = 0, a2A = 0, a3A = 0;
        float a0B = 0, a1B = 0, a2B = 0, a3B = 0;
#pragma unroll 8
        for (int jj = 0; jj < 32; jj++) {
            unsigned u = zbU[(size_t)(jb + jj) * 64];
            float Ex = bf_lo(u), Ey = bf_hi(u);
            float w0 = eBuf[w][0][jj], w1 = eBuf[w][1][jj];   // broadcasts
            float w2 = eBuf[w][2][jj], w3 = eBuf[w][3][jj];
            a0A = fmaf(w0, vrcp(fmaf(cA.x, Ex, 1.0f)), a0A);
            a1A = fmaf(w1, vrcp(fmaf(cA.y, Ex, 1.0f)), a1A);
            a2A = fmaf(w2, vrcp(fmaf(cA.z, Ex, 1.0f)), a2A);
            a3A = fmaf(w3, vrcp(fmaf(cA.w, Ex, 1.0f)), a3A);
            a0B = fmaf(w0, vrcp(fmaf(cB.x, Ey, 1.0f)), a0B);
            a1B = fmaf(w1, vrcp(fmaf(cB.y, Ey, 1.0f)), a1B);
            a2B = fmaf(w2, vrcp(fmaf(cB.z, Ey, 1.0f)), a2B);
            a3B = fmaf(w3, vrcp(fmaf(cB.w, Ey, 1.0f)), a3B);
        }
        *(float2*)&part[w][0][hp] = make_float2(a0A, a0B);
        *(float2*)&part[w][1][hp] = make_float2(a1A, a1B);
        *(float2*)&part[w][2][hp] = make_float2(a2A, a2B);
        *(float2*)&part[w][3][hp] = make_float2(a3A, a3B);
    }
    __syncthreads();

    // ---- UL reduce with folded normalization ----
    if (t < 512) {
        int r = t >> 7, h = t & 127;
        float s = 0, S = 0;
#pragma unroll
        for (int q = 0; q < 16; q++) { s += part[q][r][h]; S += sliceS[q][r]; }
        UL[r][h] = fmaf(-2.0f * vrcp(S), s, 1.0f);   // U = 1 - 2*sum/S
    }
    __syncthreads();

    // ---- E: tail GEMVs, rotated conflict-free reads ----
    {
        int kq = t & 7, h8 = t >> 3, rot = (kq >> 1) & 3;
        float4 wv[4];
        {   // agg = U@W2.T + b2
            const float4* Wp = (const float4*)(W2 + (size_t)h8 * HH) + kq * 4;
#pragma unroll
            for (int ii = 0; ii < 4; ii++) wv[ii] = Wp[(ii + rot) & 3];
            float a0 = red8(dot16r(wv, &UL[0][kq * 16], rot));
            float a1 = red8(dot16r(wv, &UL[1][kq * 16], rot));
            float a2 = red8(dot16r(wv, &UL[2][kq * 16], rot));
            float a3 = red8(dot16r(wv, &UL[3][kq * 16], rot));
            if (kq == 0) {
                float vb = b2[h8];
                aggL[0][h8] = a0 + vb; aggL[1][h8] = a1 + vb;
                aggL[2][h8] = a2 + vb; aggL[3][h8] = a3 + vb;
            }
        }
        __syncthreads();
        {   // h1 = tanh(agg@W3.T + b3)
            const float4* Wp = (const float4*)(W3 + (size_t)h8 * HH) + kq * 4;
#pragma unroll
            for (int ii = 0; ii < 4; ii++) wv[ii] = Wp[(ii + rot) & 3];
            float a0 = red8(dot16r(wv, &aggL[0][kq * 16], rot));
            float a1 = red8(dot16r(wv, &aggL[1][kq * 16], rot));
            float a2 = red8(dot16r(wv, &aggL[2][kq * 16], rot));
            float a3 = red8(dot16r(wv, &aggL[3][kq * 16], rot));
            if (kq == 0) {
                float vb = b3[h8];
                h1L[0][h8] = tanh_fast(a0 + vb); h1L[1][h8] = tanh_fast(a1 + vb);
                h1L[2][h8] = tanh_fast(a2 + vb); h1L[3][h8] = tanh_fast(a3 + vb);
            }
        }
        __syncthreads();
        {   // out = h1@W4.T + b4
            const float4* Wp = (const float4*)(W4 + (size_t)h8 * HH) + kq * 4;
#pragma unroll
            for (int ii = 0; ii < 4; ii++) wv[ii] = Wp[(ii + rot) & 3];
            float a0 = red8(dot16r(wv, &h1L[0][kq * 16], rot));
            float a1 = red8(dot16r(wv, &h1L[1][kq * 16], rot));
            float a2 = red8(dot16r(wv, &h1L[2][kq * 16], rot));
            float a3 = red8(dot16r(wv, &h1L[3][kq * 16], rot));
            if (kq == 0) {
                float vb = b4[h8];
                out[(size_t)(r0 + 0) * HH + h8] = a0 + vb;
                out[(size_t)(r0 + 1) * HH + h8] = a1 + vb;
                out[(size_t)(r0 + 2) * HH + h8] = a2 + vb;
                out[(size_t)(r0 + 3) * HH + h8] = a3 + vb;
            }
        }
    }
}

extern "C" void kernel_launch(void* const* d_in, const int* in_sizes, int n_in,
                              void* d_out, int out_size, void* d_ws, size_t ws_size,
                              hipStream_t stream) {
    const float* z   = (const float*)d_in[0];
    const float* s_t = (const float*)d_in[1];
    const float* W1  = (const float*)d_in[2];
    const float* b1  = (const float*)d_in[3];
    const float* W2  = (const float*)d_in[4];
    const float* b2  = (const float*)d_in[5];
    const float* Wq  = (const float*)d_in[6];
    const float* bq  = (const float*)d_in[7];
    const float* Wk  = (const float*)d_in[8];
    const float* bk  = (const float*)d_in[9];
    const float* W3  = (const float*)d_in[10];
    const float* b3  = (const float*)d_in[11];
    const float* W4  = (const float*)d_in[12];
    const float* b4  = (const float*)d_in[13];
    float* out = (float*)d_out;

    float* ws = (float*)d_ws;
    unsigned* kTp = (unsigned*)ws;                          // 65536 u32 [b][h][jp]
    float* qP = ws + 65536;                                 // 131072 f32 packed
    float* cP = ws + 196608;                                // 131072 f32 packed
    unsigned short* Ezj = (unsigned short*)(ws + 327680);   // 131072 bf16 [gr][h]

    hipLaunchKernelGGL(prep_kernel, dim3(256), dim3(1024), 0, stream,
                       z, s_t, W1, b1, Wq, bq, Wk, bk, qP, cP, Ezj, kTp);
    hipLaunchKernelGGL(fused_kernel, dim3(256), dim3(1024), 0, stream,
                       qP, cP, kTp, Ezj, W2, b2, W3, b3, W4, b4, out);
}